// Round 1
// baseline (51.879 us; speedup 1.0000x reference)
//
#include <hip/hip_runtime.h>
#include <math.h>

#define KWIN 8
#define BB 32
#define LL 2048
#define DD 1024
#define NSTARTS (LL - KWIN + 1)                  /* 2041 window starts */
#define CHUNK 128                                 /* window starts per block */
#define NCHUNK ((NSTARTS + CHUNK - 1) / CHUNK)    /* 16 */

__global__ __launch_bounds__(256) void hp_init_out(float* __restrict__ out, int n) {
    int i = blockIdx.x * blockDim.x + threadIdx.x;
    if (i < n) out[i] = -INFINITY;
}

// Exact float atomic-max via sign-split int atomics (max is exact -> order-independent,
// deterministic). Sign-bit test (not val>=0) so -0.0 routes to the unsigned path.
__device__ __forceinline__ void atomic_max_f32(float* addr, float val) {
    if (__float_as_int(val) >= 0) {
        atomicMax((int*)addr, __float_as_int(val));
    } else {
        atomicMin((unsigned int*)addr, __float_as_uint(val));
    }
}

__global__ __launch_bounds__(256) void hp_pool_kernel(const float* __restrict__ x,
                                                      float* __restrict__ out) {
    const int bid = blockIdx.x;
    const int b   = bid / NCHUNK;
    const int c   = bid % NCHUNK;
    const int s0  = c * CHUNK;                       // first window start for this chunk
    const int nst = min(CHUNK, NSTARTS - s0);        // 128, or 121 for the last chunk
    const int d0  = threadIdx.x * 4;                 // 4 consecutive d per thread

    const float4* xp = (const float4*)(x + (size_t)b * LL * DD + d0);
    const int rstride = DD / 4;                      // row stride in float4 units
#define ROW(l) xp[(size_t)(l) * rstride]

    // history ring: h0..h7 hold the last 8 loaded rows (static register names)
    float4 h0 = ROW(s0 + 0);
    float4 h1 = ROW(s0 + 1);
    float4 h2 = ROW(s0 + 2);
    float4 h3 = ROW(s0 + 3);
    float4 h4 = ROW(s0 + 4);
    float4 h5 = ROW(s0 + 5);
    float4 h6 = ROW(s0 + 6);
    float4 h7;

    float4 sum;
    sum.x = h0.x + h1.x + h2.x + h3.x + h4.x + h5.x + h6.x;
    sum.y = h0.y + h1.y + h2.y + h3.y + h4.y + h5.y + h6.y;
    sum.z = h0.z + h1.z + h2.z + h3.z + h4.z + h5.z + h6.z;
    sum.w = h0.w + h1.w + h2.w + h3.w + h4.w + h5.w + h6.w;

    float4 mx;
    mx.x = -INFINITY; mx.y = -INFINITY; mx.z = -INFINITY; mx.w = -INFINITY;

    // STEP: window start s0+i+J; load row l = s0+7+i+J, add, take max, subtract
    // the row leaving the window (HS = x[s0+i+J]), store new row into HD.
#define STEP_BODY(J, HS, HD)                                               \
    {                                                                      \
        float4 v = ROW(s0 + 7 + i + (J));                                  \
        sum.x += v.x; sum.y += v.y; sum.z += v.z; sum.w += v.w;            \
        mx.x = fmaxf(mx.x, sum.x); mx.y = fmaxf(mx.y, sum.y);              \
        mx.z = fmaxf(mx.z, sum.z); mx.w = fmaxf(mx.w, sum.w);              \
        sum.x -= HS.x; sum.y -= HS.y; sum.z -= HS.z; sum.w -= HS.w;        \
        HD = v;                                                            \
    }

    const int full = nst & ~7;                       // guard-free multiple-of-8 body
    for (int i = 0; i < full; i += 8) {
        STEP_BODY(0, h0, h7)
        STEP_BODY(1, h1, h0)
        STEP_BODY(2, h2, h1)
        STEP_BODY(3, h3, h2)
        STEP_BODY(4, h4, h3)
        STEP_BODY(5, h5, h4)
        STEP_BODY(6, h6, h5)
        STEP_BODY(7, h7, h6)
    }
    {   // tail (uniform scalar guards -> no divergence); ring phase is 0 again here
        int i = full;
        if (i + 0 < nst) STEP_BODY(0, h0, h7)
        if (i + 1 < nst) STEP_BODY(1, h1, h0)
        if (i + 2 < nst) STEP_BODY(2, h2, h1)
        if (i + 3 < nst) STEP_BODY(3, h3, h2)
        if (i + 4 < nst) STEP_BODY(4, h4, h3)
        if (i + 5 < nst) STEP_BODY(5, h5, h4)
        if (i + 6 < nst) STEP_BODY(6, h6, h5)
    }

    // mean = sum/8 == sum*0.125 (exact); max commutes with exact positive scale
    float* o = out + (size_t)b * DD + d0;
    atomic_max_f32(o + 0, mx.x * 0.125f);
    atomic_max_f32(o + 1, mx.y * 0.125f);
    atomic_max_f32(o + 2, mx.z * 0.125f);
    atomic_max_f32(o + 3, mx.w * 0.125f);
#undef STEP_BODY
#undef ROW
}

extern "C" void kernel_launch(void* const* d_in, const int* in_sizes, int n_in,
                              void* d_out, int out_size, void* d_ws, size_t ws_size,
                              hipStream_t stream) {
    const float* x = (const float*)d_in[0];
    float* out = (float*)d_out;

    // 1) init output to -inf (poison is 0xAA, not usable as identity)
    hp_init_out<<<(out_size + 255) / 256, 256, 0, stream>>>(out, out_size);

    // 2) chunked sliding-window mean-then-max, atomic combine across L-chunks
    hp_pool_kernel<<<BB * NCHUNK, 256, 0, stream>>>(x, out);
}

// Round 2
// 49.270 us; speedup vs baseline: 1.0530x; 1.0530x over previous
//
#include <hip/hip_runtime.h>
#include <math.h>

#define KWIN 8
#define BB 32
#define LL 2048
#define DD 1024
#define NSTARTS (LL - KWIN + 1)                  /* 2041 window starts */
#define CHUNK 128                                 /* window starts per block */
#define NCHUNK ((NSTARTS + CHUNK - 1) / CHUNK)    /* 16 */

// Exact float atomic-max via sign-split int atomics. Key order: positives by
// int asc, negatives by unsigned desc; every mutation strictly increases the
// float-order key. Init bits 0xFFFFFFFF act as -inf in BOTH paths (int -1
// loses to any positive; unsigned max loses to any negative), so a 0xFF
// memset is a valid identity -- no init kernel needed.
__device__ __forceinline__ void atomic_max_f32(float* addr, float val) {
    if (__float_as_int(val) >= 0) {
        atomicMax((int*)addr, __float_as_int(val));
    } else {
        atomicMin((unsigned int*)addr, __float_as_uint(val));
    }
}

__global__ __launch_bounds__(512) void hp_pool_kernel(const float* __restrict__ x,
                                                      float* __restrict__ out) {
    const int bid = blockIdx.x;
    const int b   = bid / NCHUNK;
    const int c   = bid % NCHUNK;
    const int s0  = c * CHUNK;                       // first window start for this chunk
    const int nst = min(CHUNK, NSTARTS - s0);        // 128, or 121 for the last chunk
    const int d0  = threadIdx.x * 2;                 // 2 consecutive d per thread

    const float2* xp = (const float2*)(x + (size_t)b * LL * DD + d0);
    const int rstride = DD / 2;                      // row stride in float2 units
#define ROW(l) xp[(size_t)(l) * rstride]

    // history ring: h0..h7 hold the last 8 loaded rows (static register names)
    float2 h0 = ROW(s0 + 0);
    float2 h1 = ROW(s0 + 1);
    float2 h2 = ROW(s0 + 2);
    float2 h3 = ROW(s0 + 3);
    float2 h4 = ROW(s0 + 4);
    float2 h5 = ROW(s0 + 5);
    float2 h6 = ROW(s0 + 6);
    float2 h7;

    float2 sum;
    sum.x = h0.x + h1.x + h2.x + h3.x + h4.x + h5.x + h6.x;
    sum.y = h0.y + h1.y + h2.y + h3.y + h4.y + h5.y + h6.y;

    float2 mx;
    mx.x = -INFINITY; mx.y = -INFINITY;

    // STEP: window start s0+i+J; load row l = s0+7+i+J, add, take max, subtract
    // the row leaving the window (HS = x[s0+i+J]), store new row into HD.
#define STEP_BODY(J, HS, HD)                                               \
    {                                                                      \
        float2 v = ROW(s0 + 7 + i + (J));                                  \
        sum.x += v.x; sum.y += v.y;                                        \
        mx.x = fmaxf(mx.x, sum.x); mx.y = fmaxf(mx.y, sum.y);              \
        sum.x -= HS.x; sum.y -= HS.y;                                      \
        HD = v;                                                            \
    }

    const int full = nst & ~7;                       // guard-free multiple-of-8 body
    for (int i = 0; i < full; i += 8) {
        STEP_BODY(0, h0, h7)
        STEP_BODY(1, h1, h0)
        STEP_BODY(2, h2, h1)
        STEP_BODY(3, h3, h2)
        STEP_BODY(4, h4, h3)
        STEP_BODY(5, h5, h4)
        STEP_BODY(6, h6, h5)
        STEP_BODY(7, h7, h6)
    }
    {   // tail (uniform scalar guards -> no divergence); ring phase is 0 again here
        int i = full;
        if (i + 0 < nst) STEP_BODY(0, h0, h7)
        if (i + 1 < nst) STEP_BODY(1, h1, h0)
        if (i + 2 < nst) STEP_BODY(2, h2, h1)
        if (i + 3 < nst) STEP_BODY(3, h3, h2)
        if (i + 4 < nst) STEP_BODY(4, h4, h3)
        if (i + 5 < nst) STEP_BODY(5, h5, h4)
        if (i + 6 < nst) STEP_BODY(6, h6, h5)
    }

    // mean = sum/8 == sum*0.125 (exact); max commutes with exact positive scale
    float* o = out + (size_t)b * DD + d0;
    atomic_max_f32(o + 0, mx.x * 0.125f);
    atomic_max_f32(o + 1, mx.y * 0.125f);
#undef STEP_BODY
#undef ROW
}

extern "C" void kernel_launch(void* const* d_in, const int* in_sizes, int n_in,
                              void* d_out, int out_size, void* d_ws, size_t ws_size,
                              hipStream_t stream) {
    const float* x = (const float*)d_in[0];
    float* out = (float*)d_out;

    // init output to 0xFFFFFFFF (-inf identity for the sign-split atomic max)
    hipMemsetAsync(out, 0xFF, (size_t)out_size * sizeof(float), stream);

    // chunked sliding-window mean-then-max, atomic combine across L-chunks.
    // 512 blocks x 512 threads = 16 waves/CU (4/SIMD) for latency hiding.
    hp_pool_kernel<<<BB * NCHUNK, 512, 0, stream>>>(x, out);
}

// Round 3
// 42.553 us; speedup vs baseline: 1.2192x; 1.1578x over previous
//
#include <hip/hip_runtime.h>
#include <math.h>

#define KWIN 8
#define BB 32
#define LL 2048
#define DD 1024
#define NSTARTS (LL - KWIN + 1)   /* 2041 */
#define NGROUP 16                 /* l-groups per block */
#define GSTART 128                /* starts per group (last group: 121) */
#define NDSL 8                    /* d-slices of 128 floats */

// Block: (b, d-slice of 128 floats). 1024 threads = 16 l-groups x 64 lanes.
// Lane owns float2 -> one wave reads one contiguous 512B row segment.
// Each group ring-walks 128 window starts; the 7 halo rows at each group
// boundary come from LDS (staged by the next group), so every element of x
// is fetched from HBM exactly once. Block-local max-reduce -> plain store.
__global__ __launch_bounds__(1024) void hp_pool_kernel(const float* __restrict__ x,
                                                       float* __restrict__ out) {
    __shared__ float2 lds[NGROUP * 7 * 64];   // halo slots; reused as max-buf

    const int b    = blockIdx.x >> 3;         // / NDSL
    const int dsl  = blockIdx.x & (NDSL - 1);
    const int t    = threadIdx.x;
    const int lane = t & 63;
    const int g    = t >> 6;                  // l-group, uniform per wave
    const int r0   = g * GSTART;              // first row / first start of group

    const float2* xp = (const float2*)(x + (size_t)b * LL * DD + dsl * 128 + lane * 2);
#define ROW(l) xp[(size_t)(l) * (DD / 2)]

    // ---- load first 7 rows; stage as halo for group g-1 ----
    float2 h0 = ROW(r0 + 0);
    float2 h1 = ROW(r0 + 1);
    float2 h2 = ROW(r0 + 2);
    float2 h3 = ROW(r0 + 3);
    float2 h4 = ROW(r0 + 4);
    float2 h5 = ROW(r0 + 5);
    float2 h6 = ROW(r0 + 6);
    float2 h7;
    lds[(g * 7 + 0) * 64 + lane] = h0;
    lds[(g * 7 + 1) * 64 + lane] = h1;
    lds[(g * 7 + 2) * 64 + lane] = h2;
    lds[(g * 7 + 3) * 64 + lane] = h3;
    lds[(g * 7 + 4) * 64 + lane] = h4;
    lds[(g * 7 + 5) * 64 + lane] = h5;
    lds[(g * 7 + 6) * 64 + lane] = h6;
    __syncthreads();

    float2 sum;
    sum.x = h0.x + h1.x + h2.x + h3.x + h4.x + h5.x + h6.x;
    sum.y = h0.y + h1.y + h2.y + h3.y + h4.y + h5.y + h6.y;
    float2 mx;
    mx.x = -INFINITY; mx.y = -INFINITY;

    // invariant before step i: sum = rows [r0+i, r0+i+6]; ring slot (i&7) holds row r0+i
#define STEP_G(J, HS, HD)                                                  \
    {                                                                      \
        float2 v = ROW(r0 + 7 + i + (J));                                  \
        sum.x += v.x; sum.y += v.y;                                        \
        mx.x = fmaxf(mx.x, sum.x); mx.y = fmaxf(mx.y, sum.y);              \
        sum.x -= HS.x; sum.y -= HS.y;                                      \
        HD = v;                                                            \
    }

    // 120 guard-free global steps (15 x 8, ring phase returns to 0)...
    for (int it = 0; it < 15; ++it) {
        const int i = it * 8;
        STEP_G(0, h0, h7)
        STEP_G(1, h1, h0)
        STEP_G(2, h2, h1)
        STEP_G(3, h3, h2)
        STEP_G(4, h4, h3)
        STEP_G(5, h5, h4)
        STEP_G(6, h6, h5)
        STEP_G(7, h7, h6)
    }
    { // ...plus step 120 (loads row r0+127): every group does exactly 121 global steps
        const int i = 120;
        STEP_G(0, h0, h7)
    }

    // steps 121..127 for groups 0..14: new row comes from group g+1's halo in LDS.
    // Ring phase after 121 steps: HS = h1..h7. Wave-uniform branch.
    if (g < NGROUP - 1) {
        const float2* halo = &lds[((g + 1) * 7) * 64 + lane];
#define STEP_L(J, HS)                                                      \
    {                                                                      \
        float2 v = halo[(J) * 64];                                         \
        sum.x += v.x; sum.y += v.y;                                        \
        mx.x = fmaxf(mx.x, sum.x); mx.y = fmaxf(mx.y, sum.y);              \
        sum.x -= HS.x; sum.y -= HS.y;                                      \
    }
        STEP_L(0, h1)
        STEP_L(1, h2)
        STEP_L(2, h3)
        STEP_L(3, h4)
        STEP_L(4, h5)
        STEP_L(5, h6)
        STEP_L(6, h7)
#undef STEP_L
    }

    // ---- block-level max reduction over the 16 groups, then one plain store ----
    __syncthreads();                     // all halo reads done; safe to reuse LDS
    lds[g * 64 + lane] = mx;
    __syncthreads();
    if (t < 64) {
        float2 m = lds[lane];
        #pragma unroll
        for (int s = 1; s < NGROUP; ++s) {
            float2 v = lds[s * 64 + lane];
            m.x = fmaxf(m.x, v.x);
            m.y = fmaxf(m.y, v.y);
        }
        // mean = sum * 0.125 (exact pow2 scale, commutes with max)
        float2 r; r.x = m.x * 0.125f; r.y = m.y * 0.125f;
        *(float2*)(out + (size_t)b * DD + dsl * 128 + lane * 2) = r;
    }
#undef STEP_G
#undef ROW
}

extern "C" void kernel_launch(void* const* d_in, const int* in_sizes, int n_in,
                              void* d_out, int out_size, void* d_ws, size_t ws_size,
                              hipStream_t stream) {
    const float* x = (const float*)d_in[0];
    float* out = (float*)d_out;
    // single kernel, 256 blocks (one per CU) x 1024 threads; no init pass needed
    hp_pool_kernel<<<BB * NDSL, 1024, 0, stream>>>(x, out);
}